// Round 1
// baseline (2339.117 us; speedup 1.0000x reference)
//
#include <hip/hip_runtime.h>
#include <math.h>

#define BB      2
#define LSEQ    2048
#define DMODEL  1024
#define DINNER  2048
#define DSTATE  16
#define DTRANK  64
#define NPROJ   96                 // DTRANK + 2*DSTATE
#define MROWS   (BB * LSEQ)        // 4096

// ---------------------------------------------------------------------------
// Generic fp32 GEMM:  C[M,N] = A[M, lda(first K cols)] @ B[N,K]^T
// 128x128 block tile, BK=8, 256 threads, 8x8 micro-tile (two 4-wide halves).
// ---------------------------------------------------------------------------
__global__ __launch_bounds__(256)
void gemm_tn(const float* __restrict__ A, const float* __restrict__ B,
             float* __restrict__ C, int M, int N, int K, int lda) {
  __shared__ float As[8][128];
  __shared__ float Bs[8][128];
  const int tid  = threadIdx.x;
  const int row0 = blockIdx.y * 128;
  const int col0 = blockIdx.x * 128;
  const int tx = tid & 15, ty = tid >> 4;
  const int lr = tid >> 1;            // 0..127 : row (A) / col (B) being staged
  const int lk = (tid & 1) * 4;       // 0 or 4 : k-quad being staged

  float acc[8][8];
#pragma unroll
  for (int i = 0; i < 8; ++i)
#pragma unroll
    for (int j = 0; j < 8; ++j) acc[i][j] = 0.f;

  const float* Aptr = A + (size_t)(row0 + lr) * lda + lk;
  const int bcol = col0 + lr;
  const float* Bptr = (bcol < N) ? (B + (size_t)bcol * K + lk) : nullptr;

  for (int k0 = 0; k0 < K; k0 += 8) {
    float4 av = *(const float4*)(Aptr + k0);
    float4 bv = make_float4(0.f, 0.f, 0.f, 0.f);
    if (Bptr) bv = *(const float4*)(Bptr + k0);
    As[lk + 0][lr] = av.x; As[lk + 1][lr] = av.y;
    As[lk + 2][lr] = av.z; As[lk + 3][lr] = av.w;
    Bs[lk + 0][lr] = bv.x; Bs[lk + 1][lr] = bv.y;
    Bs[lk + 2][lr] = bv.z; Bs[lk + 3][lr] = bv.w;
    __syncthreads();
#pragma unroll
    for (int k = 0; k < 8; ++k) {
      float a[8], b[8];
      *(float4*)&a[0] = *(const float4*)&As[k][ty * 4];
      *(float4*)&a[4] = *(const float4*)&As[k][64 + ty * 4];
      *(float4*)&b[0] = *(const float4*)&Bs[k][tx * 4];
      *(float4*)&b[4] = *(const float4*)&Bs[k][64 + tx * 4];
#pragma unroll
      for (int i = 0; i < 8; ++i)
#pragma unroll
        for (int j = 0; j < 8; ++j)
          acc[i][j] = fmaf(a[i], b[j], acc[i][j]);
    }
    __syncthreads();
  }

  // store: rows ty*4+i (half 0) and 64+ty*4+i (half 1); cols tx*4 / 64+tx*4
#pragma unroll
  for (int ih = 0; ih < 2; ++ih) {
#pragma unroll
    for (int i2 = 0; i2 < 4; ++i2) {
      int r = row0 + ih * 64 + ty * 4 + i2;
      if (r >= M) continue;
#pragma unroll
      for (int jh = 0; jh < 2; ++jh) {
        int c = col0 + jh * 64 + tx * 4;
        float4 v = make_float4(acc[ih * 4 + i2][jh * 4 + 0],
                               acc[ih * 4 + i2][jh * 4 + 1],
                               acc[ih * 4 + i2][jh * 4 + 2],
                               acc[ih * 4 + i2][jh * 4 + 3]);
        if (c + 3 < N) {
          *(float4*)(C + (size_t)r * N + c) = v;
        } else {
          float vv[4] = {v.x, v.y, v.z, v.w};
          for (int j = 0; j < 4; ++j)
            if (c + j < N) C[(size_t)r * N + c + j] = vv[j];
        }
      }
    }
  }
}

// ---------------------------------------------------------------------------
// Causal depthwise conv (k=4) + bias + SiLU.  One thread per output element.
// ---------------------------------------------------------------------------
__global__ __launch_bounds__(256)
void conv_silu_kernel(const float* __restrict__ xb, const float* __restrict__ cw,
                      const float* __restrict__ cb, float* __restrict__ xc) {
  int idx = blockIdx.x * 256 + threadIdx.x;       // over MROWS*DINNER
  int d  = idx & (DINNER - 1);
  int ml = idx >> 11;                              // DINNER = 2^11
  int l  = ml & (LSEQ - 1);
  float w0 = cw[d * 4 + 0], w1 = cw[d * 4 + 1];
  float w2 = cw[d * 4 + 2], w3 = cw[d * 4 + 3];
  const float* base = xb + (size_t)ml * DINNER + d;
  float acc = cb[d] + base[0] * w3;
  if (l >= 1) acc = fmaf(base[-DINNER],     w2, acc);
  if (l >= 2) acc = fmaf(base[-2 * DINNER], w1, acc);
  if (l >= 3) acc = fmaf(base[-3 * DINNER], w0, acc);
  xc[idx] = acc / (1.f + expf(-acc));              // SiLU
}

// ---------------------------------------------------------------------------
// Selective scan, fused with dt bias+softplus and (y + D*xc) * silu(z).
// Block = 256 thr = 4 waves; block handles one b and 16 channels (d).
// Lane layout: n = lane&15 (state), d_local = wave*4 + (lane>>4).
// Inputs staged per-64-timestep chunk through LDS.
// ---------------------------------------------------------------------------
__global__ __launch_bounds__(256)
void scan_kernel(const float* __restrict__ dtr, const float* __restrict__ xp,
                 const float* __restrict__ xc,  const float* __restrict__ z,
                 const float* __restrict__ A_log, const float* __restrict__ dt_b,
                 const float* __restrict__ Dp, float* __restrict__ y) {
  __shared__ float sdt[64][16];
  __shared__ float sxc[64][16];
  __shared__ float sz [64][16];
  __shared__ float sy [64][16];
  __shared__ float sbc[64][32];

  const int tid  = threadIdx.x;
  const int b    = blockIdx.x >> 7;            // 128 channel-groups per batch
  const int d0   = (blockIdx.x & 127) * 16;
  const int lane = tid & 63;
  const int wave = tid >> 6;
  const int n    = lane & 15;
  const int dl   = (wave << 2) | (lane >> 4);  // 0..15
  const int d    = d0 + dl;

  const float a2   = -expf(A_log[d * DSTATE + n]) * 1.44269504f;  // A * log2(e)
  const float bias = dt_b[d];
  const float Dv   = Dp[d];
  float h = 0.f;

  const int s_ld = tid >> 2;          // staging: step row
  const int p4   = (tid & 3) * 4;     // staging: 4-float column chunk

  for (int c = 0; c < LSEQ / 64; ++c) {
    const int m0 = b * LSEQ + c * 64;
    {
      size_t rowoff = (size_t)(m0 + s_ld) * DINNER + d0 + p4;
      *(float4*)&sdt[s_ld][p4] = *(const float4*)(dtr + rowoff);
      *(float4*)&sxc[s_ld][p4] = *(const float4*)(xc + rowoff);
      *(float4*)&sz [s_ld][p4] = *(const float4*)(z  + rowoff);
#pragma unroll
      for (int it = 0; it < 2; ++it) {
        int idx = tid + it * 256;
        int s = idx >> 3, q = (idx & 7) * 4;
        *(float4*)&sbc[s][q] =
            *(const float4*)(xp + (size_t)(m0 + s) * NPROJ + DTRANK + q);
      }
    }
    __syncthreads();

    for (int s = 0; s < 64; ++s) {
      float dtraw = sdt[s][dl] + bias;
      float dt = (dtraw > 20.f) ? dtraw : log1pf(expf(dtraw));   // softplus
      float xv = sxc[s][dl];
      float Bv = sbc[s][n];
      float Cv = sbc[s][16 + n];
      float dA = exp2f(dt * a2);
      h = fmaf(dA, h, dt * xv * Bv);
      float p = h * Cv;
      p += __shfl_xor(p, 1);
      p += __shfl_xor(p, 2);
      p += __shfl_xor(p, 4);
      p += __shfl_xor(p, 8);
      if (n == 0) {
        float zv = sz[s][dl];
        sy[s][dl] = (p + Dv * xv) * (zv / (1.f + expf(-zv)));
      }
    }
    __syncthreads();
    *(float4*)(y + (size_t)(m0 + s_ld) * DINNER + d0 + p4) = *(float4*)&sy[s_ld][p4];
    __syncthreads();
  }
}

// ---------------------------------------------------------------------------
extern "C" void kernel_launch(void* const* d_in, const int* in_sizes, int n_in,
                              void* d_out, int out_size, void* d_ws, size_t ws_size,
                              hipStream_t stream) {
  const float* x          = (const float*)d_in[0];
  const float* in_proj_w  = (const float*)d_in[1];
  const float* conv_w     = (const float*)d_in[2];
  const float* conv_b     = (const float*)d_in[3];
  const float* x_proj_w   = (const float*)d_in[4];
  const float* dt_proj_w  = (const float*)d_in[5];
  const float* dt_proj_b  = (const float*)d_in[6];
  const float* A_log      = (const float*)d_in[7];
  const float* D_param    = (const float*)d_in[8];
  const float* out_proj_w = (const float*)d_in[9];
  float* out = (float*)d_out;
  float* ws  = (float*)d_ws;

  // workspace layout (floats)
  float* xb  = ws;                      // [4096,2048] x_branch, later reused as y
  float* zb  = ws + 8388608;            // [4096,2048]
  float* xcb = ws + 16777216;           // [4096,2048]
  float* dtr = ws + 25165824;           // [4096,2048]
  float* xpb = ws + 33554432;           // [4096,96]

  dim3 blk(256);
  // 1. in_proj -> x_branch and z (two halves of the weight)
  gemm_tn<<<dim3(DINNER / 128, MROWS / 128), blk, 0, stream>>>(
      x, in_proj_w, xb, MROWS, DINNER, DMODEL, DMODEL);
  gemm_tn<<<dim3(DINNER / 128, MROWS / 128), blk, 0, stream>>>(
      x, in_proj_w + (size_t)DINNER * DMODEL, zb, MROWS, DINNER, DMODEL, DMODEL);
  // 2. causal depthwise conv + SiLU
  conv_silu_kernel<<<(MROWS * DINNER) / 256, blk, 0, stream>>>(xb, conv_w, conv_b, xcb);
  // 3. x_proj : [4096,2048] x [96,2048]^T -> [4096,96]
  gemm_tn<<<dim3(1, MROWS / 128), blk, 0, stream>>>(
      xcb, x_proj_w, xpb, MROWS, NPROJ, DINNER, DINNER);
  // 4. dt_proj (raw, bias+softplus fused into scan): A = xp[:, :64] (lda=96)
  gemm_tn<<<dim3(DINNER / 128, MROWS / 128), blk, 0, stream>>>(
      xpb, dt_proj_w, dtr, MROWS, DINNER, DTRANK, NPROJ);
  // 5. selective scan + gate fused; writes y over xb
  scan_kernel<<<dim3(BB * (DINNER / 16)), blk, 0, stream>>>(
      dtr, xpb, xcb, zb, A_log, dt_proj_b, D_param, xb);
  // 6. out_proj : [4096,2048] x [1024,2048]^T -> out
  gemm_tn<<<dim3(DMODEL / 128, MROWS / 128), blk, 0, stream>>>(
      xb, out_proj_w, out, MROWS, DMODEL, DINNER, DINNER);
}

// Round 2
// 2015.889 us; speedup vs baseline: 1.1603x; 1.1603x over previous
//
#include <hip/hip_runtime.h>
#include <math.h>

#define BB      2
#define LSEQ    2048
#define DMODEL  1024
#define DINNER  2048
#define DSTATE  16
#define DTRANK  64
#define NPROJ   96                 // DTRANK + 2*DSTATE
#define MROWS   (BB * LSEQ)        // 4096
#define NCHUNK  32
#define CLEN    64                 // LSEQ / NCHUNK

// ---------------------------------------------------------------------------
// Generic fp32 GEMM:  C[M,N] = A[M, lda(first K cols)] @ B[N,K]^T
// 128x128 block tile, BK=8, 256 threads, 8x8 micro-tile (two 4-wide halves).
// ---------------------------------------------------------------------------
__global__ __launch_bounds__(256)
void gemm_tn(const float* __restrict__ A, const float* __restrict__ B,
             float* __restrict__ C, int M, int N, int K, int lda) {
  __shared__ float As[8][128];
  __shared__ float Bs[8][128];
  const int tid  = threadIdx.x;
  const int row0 = blockIdx.y * 128;
  const int col0 = blockIdx.x * 128;
  const int tx = tid & 15, ty = tid >> 4;
  const int lr = tid >> 1;            // 0..127 : row (A) / col (B) being staged
  const int lk = (tid & 1) * 4;       // 0 or 4 : k-quad being staged

  float acc[8][8];
#pragma unroll
  for (int i = 0; i < 8; ++i)
#pragma unroll
    for (int j = 0; j < 8; ++j) acc[i][j] = 0.f;

  const float* Aptr = A + (size_t)(row0 + lr) * lda + lk;
  const int bcol = col0 + lr;
  const float* Bptr = (bcol < N) ? (B + (size_t)bcol * K + lk) : nullptr;

  for (int k0 = 0; k0 < K; k0 += 8) {
    float4 av = *(const float4*)(Aptr + k0);
    float4 bv = make_float4(0.f, 0.f, 0.f, 0.f);
    if (Bptr) bv = *(const float4*)(Bptr + k0);
    As[lk + 0][lr] = av.x; As[lk + 1][lr] = av.y;
    As[lk + 2][lr] = av.z; As[lk + 3][lr] = av.w;
    Bs[lk + 0][lr] = bv.x; Bs[lk + 1][lr] = bv.y;
    Bs[lk + 2][lr] = bv.z; Bs[lk + 3][lr] = bv.w;
    __syncthreads();
#pragma unroll
    for (int k = 0; k < 8; ++k) {
      float a[8], b[8];
      *(float4*)&a[0] = *(const float4*)&As[k][ty * 4];
      *(float4*)&a[4] = *(const float4*)&As[k][64 + ty * 4];
      *(float4*)&b[0] = *(const float4*)&Bs[k][tx * 4];
      *(float4*)&b[4] = *(const float4*)&Bs[k][64 + tx * 4];
#pragma unroll
      for (int i = 0; i < 8; ++i)
#pragma unroll
        for (int j = 0; j < 8; ++j)
          acc[i][j] = fmaf(a[i], b[j], acc[i][j]);
    }
    __syncthreads();
  }

#pragma unroll
  for (int ih = 0; ih < 2; ++ih) {
#pragma unroll
    for (int i2 = 0; i2 < 4; ++i2) {
      int r = row0 + ih * 64 + ty * 4 + i2;
      if (r >= M) continue;
#pragma unroll
      for (int jh = 0; jh < 2; ++jh) {
        int c = col0 + jh * 64 + tx * 4;
        float4 v = make_float4(acc[ih * 4 + i2][jh * 4 + 0],
                               acc[ih * 4 + i2][jh * 4 + 1],
                               acc[ih * 4 + i2][jh * 4 + 2],
                               acc[ih * 4 + i2][jh * 4 + 3]);
        if (c + 3 < N) {
          *(float4*)(C + (size_t)r * N + c) = v;
        } else {
          float vv[4] = {v.x, v.y, v.z, v.w};
          for (int j = 0; j < 4; ++j)
            if (c + j < N) C[(size_t)r * N + c + j] = vv[j];
        }
      }
    }
  }
}

// ---------------------------------------------------------------------------
// Causal depthwise conv (k=4) + bias + SiLU.  One thread per output element.
// ---------------------------------------------------------------------------
__global__ __launch_bounds__(256)
void conv_silu_kernel(const float* __restrict__ xb, const float* __restrict__ cw,
                      const float* __restrict__ cb, float* __restrict__ xc) {
  int idx = blockIdx.x * 256 + threadIdx.x;       // over MROWS*DINNER
  int d  = idx & (DINNER - 1);
  int ml = idx >> 11;                              // DINNER = 2^11
  int l  = ml & (LSEQ - 1);
  float w0 = cw[d * 4 + 0], w1 = cw[d * 4 + 1];
  float w2 = cw[d * 4 + 2], w3 = cw[d * 4 + 3];
  const float* base = xb + (size_t)ml * DINNER + d;
  float acc = cb[d] + base[0] * w3;
  if (l >= 1) acc = fmaf(base[-DINNER],     w2, acc);
  if (l >= 2) acc = fmaf(base[-2 * DINNER], w1, acc);
  if (l >= 3) acc = fmaf(base[-3 * DINNER], w0, acc);
  xc[idx] = acc / (1.f + expf(-acc));              // SiLU
}

// ---------------------------------------------------------------------------
// Chunked selective scan.
// Grid decode for phases A/C: bid -> dg (d-group of 16 channels), chunk c, b.
// Lane layout: n = lane&15 (state), d_local = wave*4 + (lane>>4).
// P/H layout: [b][c][dn] with dn = dg*256 + d_local*16 + n  (= dg*256 + tid).
// ---------------------------------------------------------------------------

// Phase A: per-chunk transition (P = prod dA, H = chunk scan with h_in = 0)
__global__ __launch_bounds__(256)
void scan_chunk_kernel(const float* __restrict__ dtr, const float* __restrict__ xp,
                       const float* __restrict__ xc,
                       const float* __restrict__ A_log, const float* __restrict__ dt_b,
                       float* __restrict__ P, float* __restrict__ H) {
  __shared__ float sdt[CLEN][16];
  __shared__ float sxc[CLEN][16];
  __shared__ float sB [CLEN][16];

  const int tid = threadIdx.x;
  const int bid = blockIdx.x;
  const int dg = bid & 127;
  const int c  = (bid >> 7) & (NCHUNK - 1);
  const int b  = bid >> 12;
  const int d0 = dg * 16;
  const int lane = tid & 63, wave = tid >> 6;
  const int n  = lane & 15;
  const int dl = (wave << 2) | (lane >> 4);
  const int d  = d0 + dl;
  const int m0 = b * LSEQ + c * CLEN;

  const int s_ld = tid >> 2;
  const int p4   = (tid & 3) * 4;
  {
    size_t rowoff = (size_t)(m0 + s_ld) * DINNER + d0 + p4;
    *(float4*)&sdt[s_ld][p4] = *(const float4*)(dtr + rowoff);
    *(float4*)&sxc[s_ld][p4] = *(const float4*)(xc + rowoff);
    *(float4*)&sB[s_ld][p4]  =
        *(const float4*)(xp + (size_t)(m0 + s_ld) * NPROJ + DTRANK + p4);
  }
  const float a2   = -expf(A_log[d * DSTATE + n]) * 1.44269504f;
  const float bias = dt_b[d];
  __syncthreads();

  float h = 0.f, Pa = 1.f;
#pragma unroll 4
  for (int s = 0; s < CLEN; ++s) {
    float dtraw = sdt[s][dl] + bias;
    float dt = (dtraw > 20.f) ? dtraw : log1pf(expf(dtraw));   // softplus
    float a  = exp2f(dt * a2);
    h  = fmaf(a, h, dt * sxc[s][dl] * sB[s][n]);
    Pa *= a;
  }
  size_t o = (size_t)bid * 256 + tid;
  P[o] = Pa;
  H[o] = h;
}

// Phase B: serial stitch over chunks; overwrites H[c] with h_init for chunk c.
__global__ __launch_bounds__(256)
void stitch_kernel(const float* __restrict__ P, float* __restrict__ H) {
  int idx = blockIdx.x * 256 + threadIdx.x;      // over BB*32768
  int b  = idx >> 15;
  int dn = idx & 32767;
  float h = 0.f;
  size_t base = ((size_t)b * NCHUNK << 15) + dn;
  for (int c = 0; c < NCHUNK; ++c) {
    size_t o = base + ((size_t)c << 15);
    float p = P[o], q = H[o];
    H[o] = h;                                     // h_init entering chunk c
    h = fmaf(p, h, q);
  }
}

// Phase C: recompute chunk scan seeded with h_init; fused gate + y write.
// NOTE: dtr and y may alias (block reads its tile before writing it).
__global__ __launch_bounds__(256)
void scan_out_kernel(const float* dtr, const float* __restrict__ xp,
                     const float* __restrict__ xc,  const float* __restrict__ z,
                     const float* __restrict__ A_log, const float* __restrict__ dt_b,
                     const float* __restrict__ Dp, const float* __restrict__ Hinit,
                     float* y) {
  __shared__ float sdt[CLEN][16];
  __shared__ float sxc[CLEN][16];
  __shared__ float sz [CLEN][16];
  __shared__ float sy [CLEN][16];
  __shared__ float sbc[CLEN][32];

  const int tid = threadIdx.x;
  const int bid = blockIdx.x;
  const int dg = bid & 127;
  const int c  = (bid >> 7) & (NCHUNK - 1);
  const int b  = bid >> 12;
  const int d0 = dg * 16;
  const int lane = tid & 63, wave = tid >> 6;
  const int n  = lane & 15;
  const int dl = (wave << 2) | (lane >> 4);
  const int d  = d0 + dl;
  const int m0 = b * LSEQ + c * CLEN;

  const int s_ld = tid >> 2;
  const int p4   = (tid & 3) * 4;
  {
    size_t rowoff = (size_t)(m0 + s_ld) * DINNER + d0 + p4;
    *(float4*)&sdt[s_ld][p4] = *(const float4*)(dtr + rowoff);
    *(float4*)&sxc[s_ld][p4] = *(const float4*)(xc + rowoff);
    *(float4*)&sz [s_ld][p4] = *(const float4*)(z  + rowoff);
#pragma unroll
    for (int it = 0; it < 2; ++it) {
      int idx = tid + it * 256;
      int s = idx >> 3, q = (idx & 7) * 4;
      *(float4*)&sbc[s][q] =
          *(const float4*)(xp + (size_t)(m0 + s) * NPROJ + DTRANK + q);
    }
  }
  const float a2   = -expf(A_log[d * DSTATE + n]) * 1.44269504f;
  const float bias = dt_b[d];
  const float Dv   = Dp[d];
  float h = Hinit[(size_t)bid * 256 + tid];
  __syncthreads();

  for (int s = 0; s < CLEN; ++s) {
    float dtraw = sdt[s][dl] + bias;
    float dt = (dtraw > 20.f) ? dtraw : log1pf(expf(dtraw));   // softplus
    float xv = sxc[s][dl];
    float Bv = sbc[s][n];
    float Cv = sbc[s][16 + n];
    float dA = exp2f(dt * a2);
    h = fmaf(dA, h, dt * xv * Bv);
    float p = h * Cv;
    p += __shfl_xor(p, 1);
    p += __shfl_xor(p, 2);
    p += __shfl_xor(p, 4);
    p += __shfl_xor(p, 8);
    if (n == 0) {
      float zv = sz[s][dl];
      sy[s][dl] = (p + Dv * xv) * (zv / (1.f + expf(-zv)));
    }
  }
  __syncthreads();
  *(float4*)(y + (size_t)(m0 + s_ld) * DINNER + d0 + p4) = *(float4*)&sy[s_ld][p4];
}

// ---------------------------------------------------------------------------
extern "C" void kernel_launch(void* const* d_in, const int* in_sizes, int n_in,
                              void* d_out, int out_size, void* d_ws, size_t ws_size,
                              hipStream_t stream) {
  const float* x          = (const float*)d_in[0];
  const float* in_proj_w  = (const float*)d_in[1];
  const float* conv_w     = (const float*)d_in[2];
  const float* conv_b     = (const float*)d_in[3];
  const float* x_proj_w   = (const float*)d_in[4];
  const float* dt_proj_w  = (const float*)d_in[5];
  const float* dt_proj_b  = (const float*)d_in[6];
  const float* A_log      = (const float*)d_in[7];
  const float* D_param    = (const float*)d_in[8];
  const float* out_proj_w = (const float*)d_in[9];
  float* out = (float*)d_out;
  float* ws  = (float*)d_ws;

  // workspace layout (floats); dtr and y alias xb (x_branch dead after conv,
  // phase C reads its dtr tile before overwriting it with y — block-local)
  float* xb   = ws;                      // [4096,2048] x_branch -> dtr -> y
  float* dtr  = xb;
  float* zb   = ws + 8388608;            // [4096,2048]
  float* xcb  = ws + 16777216;           // [4096,2048]
  float* xpb  = ws + 25165824;           // [4096,96]
  float* Pbuf = ws + 25559040;           // [2,32,32768]
  float* Hbuf = ws + 27656192;           // [2,32,32768]

  dim3 blk(256);
  // 1. in_proj -> x_branch and z (two halves of the weight)
  gemm_tn<<<dim3(DINNER / 128, MROWS / 128), blk, 0, stream>>>(
      x, in_proj_w, xb, MROWS, DINNER, DMODEL, DMODEL);
  gemm_tn<<<dim3(DINNER / 128, MROWS / 128), blk, 0, stream>>>(
      x, in_proj_w + (size_t)DINNER * DMODEL, zb, MROWS, DINNER, DMODEL, DMODEL);
  // 2. causal depthwise conv + SiLU
  conv_silu_kernel<<<(MROWS * DINNER) / 256, blk, 0, stream>>>(xb, conv_w, conv_b, xcb);
  // 3. x_proj : [4096,2048] x [96,2048]^T -> [4096,96]
  gemm_tn<<<dim3(1, MROWS / 128), blk, 0, stream>>>(
      xcb, x_proj_w, xpb, MROWS, NPROJ, DINNER, DINNER);
  // 4. dt_proj (raw, bias+softplus fused into scan); overwrites x_branch
  gemm_tn<<<dim3(DINNER / 128, MROWS / 128), blk, 0, stream>>>(
      xpb, dt_proj_w, dtr, MROWS, DINNER, DTRANK, NPROJ);
  // 5. chunked selective scan (A: per-chunk transition, B: stitch, C: output)
  scan_chunk_kernel<<<dim3(BB * NCHUNK * 128), blk, 0, stream>>>(
      dtr, xpb, xcb, A_log, dt_proj_b, Pbuf, Hbuf);
  stitch_kernel<<<dim3(BB * 32768 / 256), blk, 0, stream>>>(Pbuf, Hbuf);
  scan_out_kernel<<<dim3(BB * NCHUNK * 128), blk, 0, stream>>>(
      dtr, xpb, xcb, zb, A_log, dt_proj_b, D_param, Hbuf, xb);
  // 6. out_proj : [4096,2048] x [1024,2048]^T -> out
  gemm_tn<<<dim3(DMODEL / 128, MROWS / 128), blk, 0, stream>>>(
      xb, out_proj_w, out, MROWS, DMODEL, DINNER, DINNER);
}

// Round 4
// 645.772 us; speedup vs baseline: 3.6222x; 3.1217x over previous
//
#include <hip/hip_runtime.h>
#include <math.h>

#define BB      2
#define LSEQ    2048
#define DMODEL  1024
#define DINNER  2048
#define DSTATE  16
#define DTRANK  64
#define NPROJ   96                 // DTRANK + 2*DSTATE
#define MROWS   (BB * LSEQ)        // 4096
#define NCHUNK  64
#define CLEN    32                 // LSEQ / NCHUNK
#define XKS     8                  // x_proj split-K factor

typedef short bf16x8 __attribute__((ext_vector_type(8)));
typedef float f32x4  __attribute__((ext_vector_type(4)));

// ---------------------------------------------------------------------------
// Split-bf16 MFMA GEMM: C[M,N] = A[M,K] @ B[N,K]^T  (fp32 in/out, ~fp32 acc)
// A = Ah + Al (hi/lo bf16), same for B; C ≈ AhBh + AhBl + AlBh.
// 128x128 tile, BK=32, 256 thr (4 waves, 2x2), 4x4 16x16x32 frags per wave.
// M,N multiples of 128; K multiple of 32; grid = (M/128)*(N/128), %8 == 0.
// ---------------------------------------------------------------------------
struct HL { unsigned int hx, hy, lx, ly; };

__device__ __forceinline__ HL cvt4(float4 v) {
  unsigned int ux = __float_as_uint(v.x), uy = __float_as_uint(v.y);
  unsigned int uz = __float_as_uint(v.z), uw = __float_as_uint(v.w);
  unsigned int tx = ux & 0xFFFF0000u, ty = uy & 0xFFFF0000u;
  unsigned int tz = uz & 0xFFFF0000u, tw = uw & 0xFFFF0000u;
  HL r;
  r.hx = (tx >> 16) | ty;              // hi: truncated bf16 (lo corrects)
  r.hy = (tz >> 16) | tw;
  float lx = v.x - __uint_as_float(tx);
  float ly = v.y - __uint_as_float(ty);
  float lz = v.z - __uint_as_float(tz);
  float lw = v.w - __uint_as_float(tw);
  unsigned int a = __float_as_uint(lx); a += 0x7FFFu + ((a >> 16) & 1u);
  unsigned int b = __float_as_uint(ly); b += 0x7FFFu + ((b >> 16) & 1u);
  unsigned int c = __float_as_uint(lz); c += 0x7FFFu + ((c >> 16) & 1u);
  unsigned int d = __float_as_uint(lw); d += 0x7FFFu + ((d >> 16) & 1u);
  r.lx = (a >> 16) | (b & 0xFFFF0000u);
  r.ly = (c >> 16) | (d & 0xFFFF0000u);
  return r;
}

#define LDK 40   // 32 + 8 pad (16B): row stride 80B -> uniform 2-way banks

__global__ __launch_bounds__(256, 3)
void gemm_mfma(const float* __restrict__ A, const float* __restrict__ B,
               float* __restrict__ C, int M, int N, int K) {
  __shared__ __align__(16) unsigned short Ah[128][LDK];
  __shared__ __align__(16) unsigned short Al[128][LDK];
  __shared__ __align__(16) unsigned short Bh[128][LDK];
  __shared__ __align__(16) unsigned short Bl[128][LDK];

  const int tid = threadIdx.x;
  // bijective XCD swizzle (gridDim.x % 8 == 0)
  const int nbx = N >> 7;
  const int qq  = gridDim.x >> 3;
  int flat = blockIdx.x;
  flat = (flat & 7) * qq + (flat >> 3);
  const int bx = flat % nbx, by = flat / nbx;
  const int row0 = by * 128, col0 = bx * 128;

  const int lane = tid & 63, wid = tid >> 6;
  const int wr = wid >> 1, wc = wid & 1;
  const int fr = lane & 15;            // fragment row (A) / col (B)
  const int fk = (lane >> 4) * 8;      // fragment k offset

  const int srow = tid >> 1;           // staging row 0..127
  const int sk16 = (tid & 1) * 16;     // staging k sub-block (16 floats)
  const float* aB = A + (size_t)(row0 + srow) * K + sk16;
  const float* bB = B + (size_t)(col0 + srow) * K + sk16;

  f32x4 acc[4][4] = {};

  for (int k0 = 0; k0 < K; k0 += 32) {
    __syncthreads();                   // previous compute done; LDS reusable
    {
      float4 a0 = *(const float4*)(aB + k0);
      float4 a1 = *(const float4*)(aB + k0 + 4);
      float4 a2 = *(const float4*)(aB + k0 + 8);
      float4 a3 = *(const float4*)(aB + k0 + 12);
      float4 b0 = *(const float4*)(bB + k0);
      float4 b1 = *(const float4*)(bB + k0 + 4);
      float4 b2 = *(const float4*)(bB + k0 + 8);
      float4 b3 = *(const float4*)(bB + k0 + 12);
      HL c0 = cvt4(a0), c1 = cvt4(a1), c2 = cvt4(a2), c3 = cvt4(a3);
      *(uint4*)&Ah[srow][sk16]     = make_uint4(c0.hx, c0.hy, c1.hx, c1.hy);
      *(uint4*)&Ah[srow][sk16 + 8] = make_uint4(c2.hx, c2.hy, c3.hx, c3.hy);
      *(uint4*)&Al[srow][sk16]     = make_uint4(c0.lx, c0.ly, c1.lx, c1.ly);
      *(uint4*)&Al[srow][sk16 + 8] = make_uint4(c2.lx, c2.ly, c3.lx, c3.ly);
      HL d0 = cvt4(b0), d1 = cvt4(b1), d2 = cvt4(b2), d3 = cvt4(b3);
      *(uint4*)&Bh[srow][sk16]     = make_uint4(d0.hx, d0.hy, d1.hx, d1.hy);
      *(uint4*)&Bh[srow][sk16 + 8] = make_uint4(d2.hx, d2.hy, d3.hx, d3.hy);
      *(uint4*)&Bl[srow][sk16]     = make_uint4(d0.lx, d0.ly, d1.lx, d1.ly);
      *(uint4*)&Bl[srow][sk16 + 8] = make_uint4(d2.lx, d2.ly, d3.lx, d3.ly);
    }
    __syncthreads();

    bf16x8 bh[4], bl[4];
#pragma unroll
    for (int j = 0; j < 4; ++j) {
      bh[j] = *(const bf16x8*)&Bh[wc * 64 + j * 16 + fr][fk];
      bl[j] = *(const bf16x8*)&Bl[wc * 64 + j * 16 + fr][fk];
    }
#pragma unroll
    for (int i = 0; i < 4; ++i) {
      bf16x8 ah = *(const bf16x8*)&Ah[wr * 64 + i * 16 + fr][fk];
      bf16x8 al = *(const bf16x8*)&Al[wr * 64 + i * 16 + fr][fk];
#pragma unroll
      for (int j = 0; j < 4; ++j) {
        acc[i][j] = __builtin_amdgcn_mfma_f32_16x16x32_bf16(al, bh[j], acc[i][j], 0, 0, 0);
        acc[i][j] = __builtin_amdgcn_mfma_f32_16x16x32_bf16(ah, bl[j], acc[i][j], 0, 0, 0);
        acc[i][j] = __builtin_amdgcn_mfma_f32_16x16x32_bf16(ah, bh[j], acc[i][j], 0, 0, 0);
      }
    }
  }

  // C/D layout (m89-verified): col = lane&15, row = (lane>>4)*4 + reg
#pragma unroll
  for (int i = 0; i < 4; ++i) {
    const int rbase = row0 + wr * 64 + i * 16 + (lane >> 4) * 4;
#pragma unroll
    for (int j = 0; j < 4; ++j) {
      const int cc = col0 + wc * 64 + j * 16 + fr;
#pragma unroll
      for (int r = 0; r < 4; ++r)
        C[(size_t)(rbase + r) * N + cc] = acc[i][j][r];
    }
  }
}

// ---------------------------------------------------------------------------
// fp32 GEMM (kept for dt_proj only): C = softplus(A@B^T + bias[col])
// ---------------------------------------------------------------------------
template <int ACT>
__global__ __launch_bounds__(256)
void gemm_tn(const float* __restrict__ A, const float* __restrict__ B,
             float* __restrict__ C, const float* __restrict__ bias,
             int M, int N, int K, int lda) {
  __shared__ float As[8][128];
  __shared__ float Bs[8][128];
  const int tid  = threadIdx.x;
  const int row0 = blockIdx.y * 128;
  const int col0 = blockIdx.x * 128;
  const int tx = tid & 15, ty = tid >> 4;
  const int lr = tid >> 1;
  const int lk = (tid & 1) * 4;

  float acc[8][8];
#pragma unroll
  for (int i = 0; i < 8; ++i)
#pragma unroll
    for (int j = 0; j < 8; ++j) acc[i][j] = 0.f;

  const float* Aptr = A + (size_t)(row0 + lr) * lda + lk;
  const int bcol = col0 + lr;
  const float* Bptr = (bcol < N) ? (B + (size_t)bcol * K + lk) : nullptr;

  for (int k0 = 0; k0 < K; k0 += 8) {
    float4 av = *(const float4*)(Aptr + k0);
    float4 bv = make_float4(0.f, 0.f, 0.f, 0.f);
    if (Bptr) bv = *(const float4*)(Bptr + k0);
    As[lk + 0][lr] = av.x; As[lk + 1][lr] = av.y;
    As[lk + 2][lr] = av.z; As[lk + 3][lr] = av.w;
    Bs[lk + 0][lr] = bv.x; Bs[lk + 1][lr] = bv.y;
    Bs[lk + 2][lr] = bv.z; Bs[lk + 3][lr] = bv.w;
    __syncthreads();
#pragma unroll
    for (int k = 0; k < 8; ++k) {
      float a[8], b[8];
      *(float4*)&a[0] = *(const float4*)&As[k][ty * 4];
      *(float4*)&a[4] = *(const float4*)&As[k][64 + ty * 4];
      *(float4*)&b[0] = *(const float4*)&Bs[k][tx * 4];
      *(float4*)&b[4] = *(const float4*)&Bs[k][64 + tx * 4];
#pragma unroll
      for (int i = 0; i < 8; ++i)
#pragma unroll
        for (int j = 0; j < 8; ++j)
          acc[i][j] = fmaf(a[i], b[j], acc[i][j]);
    }
    __syncthreads();
  }

#pragma unroll
  for (int ih = 0; ih < 2; ++ih) {
#pragma unroll
    for (int i2 = 0; i2 < 4; ++i2) {
      int r = row0 + ih * 64 + ty * 4 + i2;
      if (r >= M) continue;
#pragma unroll
      for (int jh = 0; jh < 2; ++jh) {
        int c = col0 + jh * 64 + tx * 4;
        float vv[4];
#pragma unroll
        for (int j = 0; j < 4; ++j) {
          float v = acc[ih * 4 + i2][jh * 4 + j];
          if (ACT == 1) {
            v += bias[c + j];
            v = (v > 20.f) ? v : log1pf(expf(v));   // softplus
          }
          vv[j] = v;
        }
        if (c + 3 < N) {
          *(float4*)(C + (size_t)r * N + c) = make_float4(vv[0], vv[1], vv[2], vv[3]);
        } else {
          for (int j = 0; j < 4; ++j)
            if (c + j < N) C[(size_t)r * N + c + j] = vv[j];
        }
      }
    }
  }
}

// ---------------------------------------------------------------------------
// x_proj split-K GEMM: C[4096,96] += A[4096, kslice] @ W[96, kslice]^T
// ---------------------------------------------------------------------------
__global__ __launch_bounds__(256)
void xproj_splitk(const float* __restrict__ A, const float* __restrict__ W,
                  float* __restrict__ C) {
  __shared__ float As[8][128];
  __shared__ float Ws[8][96];
  const int tid  = threadIdx.x;
  const int row0 = blockIdx.x * 128;
  const int k0b  = blockIdx.y * (DINNER / XKS);
  const int tx = tid & 15, ty = tid >> 4;
  const int lr = tid >> 1, lk = (tid & 1) * 4;

  float acc[8][6];
#pragma unroll
  for (int i = 0; i < 8; ++i)
#pragma unroll
    for (int j = 0; j < 6; ++j) acc[i][j] = 0.f;

  for (int k0 = k0b; k0 < k0b + DINNER / XKS; k0 += 8) {
    float4 av = *(const float4*)(A + (size_t)(row0 + lr) * DINNER + k0 + lk);
    As[lk + 0][lr] = av.x; As[lk + 1][lr] = av.y;
    As[lk + 2][lr] = av.z; As[lk + 3][lr] = av.w;
    if (tid < 192) {
      int j = tid >> 1, kk = (tid & 1) * 4;
      float4 wv = *(const float4*)(W + (size_t)j * DINNER + k0 + kk);
      Ws[kk + 0][j] = wv.x; Ws[kk + 1][j] = wv.y;
      Ws[kk + 2][j] = wv.z; Ws[kk + 3][j] = wv.w;
    }
    __syncthreads();
#pragma unroll
    for (int kk = 0; kk < 8; ++kk) {
      float a[8], w[6];
      *(float4*)&a[0] = *(const float4*)&As[kk][ty * 8];
      *(float4*)&a[4] = *(const float4*)&As[kk][ty * 8 + 4];
#pragma unroll
      for (int j = 0; j < 6; ++j) w[j] = Ws[kk][tx * 6 + j];
#pragma unroll
      for (int i = 0; i < 8; ++i)
#pragma unroll
        for (int j = 0; j < 6; ++j)
          acc[i][j] = fmaf(a[i], w[j], acc[i][j]);
    }
    __syncthreads();
  }
#pragma unroll
  for (int i = 0; i < 8; ++i)
#pragma unroll
    for (int j = 0; j < 6; ++j)
      atomicAdd(&C[(size_t)(row0 + ty * 8 + i) * NPROJ + tx * 6 + j], acc[i][j]);
}

// ---------------------------------------------------------------------------
// Causal depthwise conv (k=4) + bias + SiLU.
// ---------------------------------------------------------------------------
__global__ __launch_bounds__(256)
void conv_silu_kernel(const float* __restrict__ xb, const float* __restrict__ cw,
                      const float* __restrict__ cb, float* __restrict__ xc) {
  int idx = blockIdx.x * 256 + threadIdx.x;
  int d  = idx & (DINNER - 1);
  int ml = idx >> 11;
  int l  = ml & (LSEQ - 1);
  float w0 = cw[d * 4 + 0], w1 = cw[d * 4 + 1];
  float w2 = cw[d * 4 + 2], w3 = cw[d * 4 + 3];
  const float* base = xb + (size_t)ml * DINNER + d;
  float acc = cb[d] + base[0] * w3;
  if (l >= 1) acc = fmaf(base[-DINNER],     w2, acc);
  if (l >= 2) acc = fmaf(base[-2 * DINNER], w1, acc);
  if (l >= 3) acc = fmaf(base[-3 * DINNER], w0, acc);
  xc[idx] = acc / (1.f + expf(-acc));
}

// ---------------------------------------------------------------------------
// Chunked scan, h[16] in registers, one thread per (b, chunk, d).
// grid = 1024: bid -> b = bid>>9, c = (bid>>3)&63, dg = bid&7; d = dg*256+tid.
// dt input is POST-softplus. P/H layout: [b][c][d][16].
// ---------------------------------------------------------------------------
__global__ __launch_bounds__(256)
void scan_chunk_kernel(const float* __restrict__ dt, const float* __restrict__ xp,
                       const float* __restrict__ xc, const float* __restrict__ A_log,
                       float* __restrict__ P, float* __restrict__ H) {
  __shared__ float sbc[CLEN][32];
  const int tid = threadIdx.x;
  const int bid = blockIdx.x;
  const int b  = bid >> 9;
  const int c  = (bid >> 3) & 63;
  const int dg = bid & 7;
  const int d  = dg * 256 + tid;
  const int m0 = b * LSEQ + c * CLEN;
  {
    int r = tid >> 3, q = (tid & 7) * 4;
    *(float4*)&sbc[r][q] = *(const float4*)(xp + (size_t)(m0 + r) * NPROJ + DTRANK + q);
  }
  float a2[DSTATE], h[DSTATE];
#pragma unroll
  for (int n = 0; n < DSTATE; ++n) {
    a2[n] = -expf(A_log[d * DSTATE + n]) * 1.44269504f;
    h[n] = 0.f;
  }
  float dtsum = 0.f;
  __syncthreads();

  const float* dtp = dt + (size_t)m0 * DINNER + d;
  const float* xcp = xc + (size_t)m0 * DINNER + d;
  float ndt = dtp[0], nxc = xcp[0];
  for (int s = 0; s < CLEN; ++s) {
    float dtv = ndt, xv = nxc;
    int sp = (s + 1 < CLEN) ? s + 1 : s;
    ndt = dtp[(size_t)sp * DINNER];
    nxc = xcp[(size_t)sp * DINNER];
    dtsum += dtv;
    float dtx = dtv * xv;
    float Bv[16];
    *(float4*)&Bv[0]  = *(const float4*)&sbc[s][0];
    *(float4*)&Bv[4]  = *(const float4*)&sbc[s][4];
    *(float4*)&Bv[8]  = *(const float4*)&sbc[s][8];
    *(float4*)&Bv[12] = *(const float4*)&sbc[s][12];
#pragma unroll
    for (int n = 0; n < DSTATE; ++n) {
      float a = exp2f(dtv * a2[n]);
      h[n] = fmaf(a, h[n], dtx * Bv[n]);
    }
  }
  size_t o = ((size_t)(b * NCHUNK + c) * DINNER + d) * DSTATE;
  float4* Hp = (float4*)(H + o);
  Hp[0] = make_float4(h[0], h[1], h[2], h[3]);
  Hp[1] = make_float4(h[4], h[5], h[6], h[7]);
  Hp[2] = make_float4(h[8], h[9], h[10], h[11]);
  Hp[3] = make_float4(h[12], h[13], h[14], h[15]);
  float p[16];
#pragma unroll
  for (int n = 0; n < DSTATE; ++n) p[n] = exp2f(a2[n] * dtsum);
  float4* Pp = (float4*)(P + o);
  Pp[0] = make_float4(p[0], p[1], p[2], p[3]);
  Pp[1] = make_float4(p[4], p[5], p[6], p[7]);
  Pp[2] = make_float4(p[8], p[9], p[10], p[11]);
  Pp[3] = make_float4(p[12], p[13], p[14], p[15]);
}

// ---------------------------------------------------------------------------
// Stitch: serial over chunks per (b, d, n); overwrites H[c] with h_init.
// ---------------------------------------------------------------------------
__global__ __launch_bounds__(256)
void stitch_kernel(const float* __restrict__ P, float* __restrict__ H) {
  int idx = blockIdx.x * 256 + threadIdx.x;      // 65536 = BB * DINNER * 16
  int b = idx >> 15, e = idx & 32767;
  size_t base = (size_t)b * NCHUNK * 32768 + e;
  float h = 0.f;
  for (int c = 0; c < NCHUNK; ++c) {
    size_t o = base + (size_t)c * 32768;
    float p = P[o], q = H[o];
    H[o] = h;
    h = fmaf(p, h, q);
  }
}

// ---------------------------------------------------------------------------
// Output scan: recompute seeded with h_init, fused D-skip + silu(z) gate.
// dt and y alias (same buffer): each thread reads row s+1 before writing row s.
// ---------------------------------------------------------------------------
__global__ __launch_bounds__(256)
void scan_out_kernel(const float* dt, const float* __restrict__ xp,
                     const float* __restrict__ xc, const float* __restrict__ z,
                     const float* __restrict__ A_log, const float* __restrict__ Dp,
                     const float* __restrict__ Hinit, float* y) {
  __shared__ float sbc[CLEN][32];
  const int tid = threadIdx.x;
  const int bid = blockIdx.x;
  const int b  = bid >> 9;
  const int c  = (bid >> 3) & 63;
  const int dg = bid & 7;
  const int d  = dg * 256 + tid;
  const int m0 = b * LSEQ + c * CLEN;
  {
    int r = tid >> 3, q = (tid & 7) * 4;
    *(float4*)&sbc[r][q] = *(const float4*)(xp + (size_t)(m0 + r) * NPROJ + DTRANK + q);
  }
  float a2[DSTATE], h[DSTATE];
  size_t ho = ((size_t)(b * NCHUNK + c) * DINNER + d) * DSTATE;
  const float4* Hp = (const float4*)(Hinit + ho);
  float4 h0 = Hp[0], h1 = Hp[1], h2 = Hp[2], h3 = Hp[3];
  h[0]=h0.x; h[1]=h0.y; h[2]=h0.z; h[3]=h0.w;
  h[4]=h1.x; h[5]=h1.y; h[6]=h1.z; h[7]=h1.w;
  h[8]=h2.x; h[9]=h2.y; h[10]=h2.z; h[11]=h2.w;
  h[12]=h3.x; h[13]=h3.y; h[14]=h3.z; h[15]=h3.w;
#pragma unroll
  for (int n = 0; n < DSTATE; ++n)
    a2[n] = -expf(A_log[d * DSTATE + n]) * 1.44269504f;
  const float Dv = Dp[d];
  __syncthreads();

  const float* dtp = dt + (size_t)m0 * DINNER + d;
  const float* xcp = xc + (size_t)m0 * DINNER + d;
  const float* zp  = z  + (size_t)m0 * DINNER + d;
  float* yp = y + (size_t)m0 * DINNER + d;
  float ndt = dtp[0], nxc = xcp[0], nz = zp[0];
  for (int s = 0; s < CLEN; ++s) {
    float dtv = ndt, xv = nxc, zv = nz;
    int sp = (s + 1 < CLEN) ? s + 1 : s;
    ndt = dtp[(size_t)sp * DINNER];
    nxc = xcp[(size_t)sp * DINNER];
    nz  = zp[(size_t)sp * DINNER];
    float dtx = dtv * xv;
    float Bv[16], Cv[16];
    *(float4*)&Bv[0]  = *(const float4*)&sbc[s][0];
    *(float4*)&Bv[4]  = *(const float4*)&sbc[s][4];
    *(float4*)&Bv[8]  = *(const float4*)&sbc[s][8];
    *(float4*)&Bv[12] = *(const float4*)&sbc[s][12];
    *(float4*)&Cv[0]  = *(const float4*)&sbc[s][16];
    *(float4*)&Cv[4]  = *(const float4*)&sbc[s][20];
    *(float4*)&Cv[8]  = *(const float4*)&sbc[s][24];
    *(float4*)&Cv[12] = *(const float4*)&sbc[s][28];
    float yv = 0.f;
#pragma unroll
    for (int n = 0; n < DSTATE; ++n) {
      float a = exp2f(dtv * a2[n]);
      h[n] = fmaf(a, h[n], dtx * Bv[n]);
      yv = fmaf(h[n], Cv[n], yv);
    }
    yv = (yv + Dv * xv) * (zv / (1.f + expf(-zv)));
    yp[(size_t)s * DINNER] = yv;
  }
}

// ---------------------------------------------------------------------------
extern "C" void kernel_launch(void* const* d_in, const int* in_sizes, int n_in,
                              void* d_out, int out_size, void* d_ws, size_t ws_size,
                              hipStream_t stream) {
  const float* x          = (const float*)d_in[0];
  const float* in_proj_w  = (const float*)d_in[1];
  const float* conv_w     = (const float*)d_in[2];
  const float* conv_b     = (const float*)d_in[3];
  const float* x_proj_w   = (const float*)d_in[4];
  const float* dt_proj_w  = (const float*)d_in[5];
  const float* dt_proj_b  = (const float*)d_in[6];
  const float* A_log      = (const float*)d_in[7];
  const float* D_param    = (const float*)d_in[8];
  const float* out_proj_w = (const float*)d_in[9];
  float* out = (float*)d_out;
  float* ws  = (float*)d_ws;

  // workspace (floats); dtr and y alias xb
  float* xb   = ws;                      // [4096,2048] x_branch -> dt -> y
  float* dtr  = xb;
  float* zb   = ws + 8388608;            // [4096,2048]
  float* xcb  = ws + 16777216;           // [4096,2048]
  float* xpb  = ws + 25165824;           // [4096,96]
  float* Pbuf = ws + 25559040;           // [2,64,2048,16]
  float* Hbuf = ws + 29753344;           // [2,64,2048,16]

  dim3 blk(256);
  hipMemsetAsync(xpb, 0, (size_t)MROWS * NPROJ * sizeof(float), stream);
  // 1. in_proj -> x_branch and z (split-bf16 MFMA)
  gemm_mfma<<<dim3((MROWS / 128) * (DINNER / 128)), blk, 0, stream>>>(
      x, in_proj_w, xb, MROWS, DINNER, DMODEL);
  gemm_mfma<<<dim3((MROWS / 128) * (DINNER / 128)), blk, 0, stream>>>(
      x, in_proj_w + (size_t)DINNER * DMODEL, zb, MROWS, DINNER, DMODEL);
  // 2. causal depthwise conv + SiLU
  conv_silu_kernel<<<(MROWS * DINNER) / 256, blk, 0, stream>>>(xb, conv_w, conv_b, xcb);
  // 3. x_proj split-K with atomics
  xproj_splitk<<<dim3(MROWS / 128, XKS), blk, 0, stream>>>(xcb, x_proj_w, xpb);
  // 4. dt_proj with fused bias+softplus; overwrites x_branch
  gemm_tn<1><<<dim3(DINNER / 128, MROWS / 128), blk, 0, stream>>>(
      xpb, dt_proj_w, dtr, dt_proj_b, MROWS, DINNER, DTRANK, NPROJ);
  // 5. chunked scan: A (chunk transitions), B (stitch), C (output + gate)
  scan_chunk_kernel<<<dim3(BB * NCHUNK * 8), blk, 0, stream>>>(
      dtr, xpb, xcb, A_log, Pbuf, Hbuf);
  stitch_kernel<<<dim3(BB * DINNER * DSTATE / 256), blk, 0, stream>>>(Pbuf, Hbuf);
  scan_out_kernel<<<dim3(BB * NCHUNK * 8), blk, 0, stream>>>(
      dtr, xpb, xcb, zb, A_log, D_param, Hbuf, xb);
  // 6. out_proj (split-bf16 MFMA)
  gemm_mfma<<<dim3((MROWS / 128) * (DMODEL / 128)), blk, 0, stream>>>(
      xb, out_proj_w, out, MROWS, DMODEL, DINNER);
}

// Round 6
// 518.022 us; speedup vs baseline: 4.5155x; 1.2466x over previous
//
#include <hip/hip_runtime.h>
#include <math.h>

#define BB      2
#define LSEQ    2048
#define DMODEL  1024
#define DINNER  2048
#define DSTATE  16
#define DTRANK  64
#define NPROJ   96                 // DTRANK + 2*DSTATE
#define MROWS   (BB * LSEQ)        // 4096
#define NCHUNK  64
#define CLEN    32                 // LSEQ / NCHUNK
#define XKS     16                 // x_proj split-K factor (128-wide slices)

typedef short bf16x8 __attribute__((ext_vector_type(8)));
typedef float f32x4  __attribute__((ext_vector_type(4)));

// ---------------------------------------------------------------------------
// Split-bf16 MFMA GEMM: C = A[M,K] @ B[N,K]^T (fp32 in/out, ~fp32 accuracy)
// A = Ah + Al, B = Bh + Bl; C ≈ AhBh + AhBl + AlBh.
// 128x128 tile, BK=32, 256 thr (4 waves 2x2), 4x4 16x16x32 frags per wave.
// LDS double-buffered (64 KB), XOR-swizzled (conflict-free), reg prefetch.
// Dual output: cols < Nout -> C0, cols >= Nout -> C1 (both row-stride Nout).
// M,N mult of 128; K mult of 32; grid = (M/128)*(N/128), % 8 == 0.
// ---------------------------------------------------------------------------
struct HL { unsigned int hx, hy, lx, ly; };

__device__ __forceinline__ HL cvt4(float4 v) {
  unsigned int ux = __float_as_uint(v.x), uy = __float_as_uint(v.y);
  unsigned int uz = __float_as_uint(v.z), uw = __float_as_uint(v.w);
  unsigned int tx = ux & 0xFFFF0000u, ty = uy & 0xFFFF0000u;
  unsigned int tz = uz & 0xFFFF0000u, tw = uw & 0xFFFF0000u;
  HL r;
  r.hx = (tx >> 16) | ty;              // hi: truncated bf16 (lo corrects)
  r.hy = (tz >> 16) | tw;
  float lx = v.x - __uint_as_float(tx);
  float ly = v.y - __uint_as_float(ty);
  float lz = v.z - __uint_as_float(tz);
  float lw = v.w - __uint_as_float(tw);
  unsigned int a = __float_as_uint(lx); a += 0x7FFFu + ((a >> 16) & 1u);
  unsigned int b = __float_as_uint(ly); b += 0x7FFFu + ((b >> 16) & 1u);
  unsigned int c = __float_as_uint(lz); c += 0x7FFFu + ((c >> 16) & 1u);
  unsigned int d = __float_as_uint(lw); d += 0x7FFFu + ((d >> 16) & 1u);
  r.lx = (a >> 16) | (b & 0xFFFF0000u);
  r.ly = (c >> 16) | (d & 0xFFFF0000u);
  return r;
}

// stage one 128x32 fp32 tile (A and B) into h/l bf16 LDS, swizzled.
// Row = 64 B = 4 slots of 16 B; physical slot = logical slot ^ ((row>>1)&3).
__device__ __forceinline__ void stage2(unsigned short (*S)[128 * 32], int srow,
                                       int skf, const float4* va, const float4* vb) {
  const int sw = (srow >> 1) & 3;
  const int s0 = skf >> 3;             // 0 or 2
  const int o0 = srow * 32 + ((s0 ^ sw) << 3);
  const int o1 = srow * 32 + (((s0 + 1) ^ sw) << 3);
  HL a0 = cvt4(va[0]), a1 = cvt4(va[1]), a2 = cvt4(va[2]), a3 = cvt4(va[3]);
  *(uint4*)(S[0] + o0) = make_uint4(a0.hx, a0.hy, a1.hx, a1.hy);
  *(uint4*)(S[0] + o1) = make_uint4(a2.hx, a2.hy, a3.hx, a3.hy);
  *(uint4*)(S[1] + o0) = make_uint4(a0.lx, a0.ly, a1.lx, a1.ly);
  *(uint4*)(S[1] + o1) = make_uint4(a2.lx, a2.ly, a3.lx, a3.ly);
  HL b0 = cvt4(vb[0]), b1 = cvt4(vb[1]), b2 = cvt4(vb[2]), b3 = cvt4(vb[3]);
  *(uint4*)(S[2] + o0) = make_uint4(b0.hx, b0.hy, b1.hx, b1.hy);
  *(uint4*)(S[2] + o1) = make_uint4(b2.hx, b2.hy, b3.hx, b3.hy);
  *(uint4*)(S[3] + o0) = make_uint4(b0.lx, b0.ly, b1.lx, b1.ly);
  *(uint4*)(S[3] + o1) = make_uint4(b2.lx, b2.ly, b3.lx, b3.ly);
}

__global__ __launch_bounds__(256, 2)
void gemm_mfma(const float* __restrict__ A, const float* __restrict__ B,
               float* __restrict__ C0, float* __restrict__ C1,
               int M, int N, int K, int Nout) {
  __shared__ __align__(16) unsigned short SH[2][4][128 * 32];   // 64 KB

  const int tid = threadIdx.x;
  const int nbx = N >> 7;
  const int qq  = gridDim.x >> 3;      // grid % 8 == 0
  int flat = blockIdx.x;
  flat = (flat & 7) * qq + (flat >> 3);
  const int bx = flat % nbx, by = flat / nbx;
  const int row0 = by * 128, col0 = bx * 128;

  const int lane = tid & 63, wid = tid >> 6;
  const int wr = wid >> 1, wc = wid & 1;
  const int fr = lane & 15;            // fragment row (A) / col (B)
  const int g  = lane >> 4;            // k-slot group

  const int srow = tid >> 1;           // staging row 0..127
  const int skf  = (tid & 1) * 16;     // staging k offset (elements)
  const float* aB = A + (size_t)(row0 + srow) * K + skf;
  const float* bB = B + (size_t)(col0 + srow) * K + skf;

  f32x4 acc[4][4] = {};
  const int NT = K >> 5;

  float4 cva[4], cvb[4];
#pragma unroll
  for (int q = 0; q < 4; ++q) {
    cva[q] = *(const float4*)(aB + q * 4);
    cvb[q] = *(const float4*)(bB + q * 4);
  }
  stage2(SH[0], srow, skf, cva, cvb);
#pragma unroll
  for (int q = 0; q < 4; ++q) {        // prefetch tile 1 (NT >= 2 always here)
    cva[q] = *(const float4*)(aB + 32 + q * 4);
    cvb[q] = *(const float4*)(bB + 32 + q * 4);
  }
  __syncthreads();

  int p = 0;
  for (int t = 0; t < NT; ++t) {
    bf16x8 bh[4], bl[4], ah[4], al[4];
#pragma unroll
    for (int j = 0; j < 4; ++j) {
      const int rb = wc * 64 + j * 16 + fr;
      const int ob = rb * 32 + (((g ^ (rb >> 1)) & 3) << 3);
      bh[j] = *(const bf16x8*)(SH[p][2] + ob);
      bl[j] = *(const bf16x8*)(SH[p][3] + ob);
    }
#pragma unroll
    for (int i = 0; i < 4; ++i) {
      const int ra = wr * 64 + i * 16 + fr;
      const int oa = ra * 32 + (((g ^ (ra >> 1)) & 3) << 3);
      ah[i] = *(const bf16x8*)(SH[p][0] + oa);
      al[i] = *(const bf16x8*)(SH[p][1] + oa);
    }
    if (t + 1 < NT) stage2(SH[p ^ 1], srow, skf, cva, cvb);
    if (t + 2 < NT) {
      const float* ap = aB + (size_t)(t + 2) * 32;
      const float* bp = bB + (size_t)(t + 2) * 32;
#pragma unroll
      for (int q = 0; q < 4; ++q) {
        cva[q] = *(const float4*)(ap + q * 4);
        cvb[q] = *(const float4*)(bp + q * 4);
      }
    }
#pragma unroll
    for (int i = 0; i < 4; ++i)
#pragma unroll
      for (int j = 0; j < 4; ++j) {
        acc[i][j] = __builtin_amdgcn_mfma_f32_16x16x32_bf16(al[i], bh[j], acc[i][j], 0, 0, 0);
        acc[i][j] = __builtin_amdgcn_mfma_f32_16x16x32_bf16(ah[i], bl[j], acc[i][j], 0, 0, 0);
        acc[i][j] = __builtin_amdgcn_mfma_f32_16x16x32_bf16(ah[i], bh[j], acc[i][j], 0, 0, 0);
      }
    __syncthreads();
    p ^= 1;
  }

  // C/D layout (m89-verified): col = lane&15, row = (lane>>4)*4 + reg
  float* Cd;
  int cc0;
  if (C1 != nullptr && col0 >= Nout) { Cd = C1; cc0 = col0 - Nout; }
  else                               { Cd = C0; cc0 = col0; }
#pragma unroll
  for (int i = 0; i < 4; ++i) {
    const int rbase = row0 + wr * 64 + i * 16 + (lane >> 4) * 4;
#pragma unroll
    for (int j = 0; j < 4; ++j) {
      const int cc = cc0 + wc * 64 + j * 16 + fr;
#pragma unroll
      for (int r = 0; r < 4; ++r)
        Cd[(size_t)(rbase + r) * Nout + cc] = acc[i][j][r];
    }
  }
}

// ---------------------------------------------------------------------------
// fp32 GEMM (dt_proj only): C = softplus(A@B^T + bias[col]); reg prefetch.
// ---------------------------------------------------------------------------
template <int ACT>
__global__ __launch_bounds__(256)
void gemm_tn(const float* __restrict__ A, const float* __restrict__ B,
             float* __restrict__ C, const float* __restrict__ bias,
             int M, int N, int K, int lda) {
  __shared__ float As[8][128];
  __shared__ float Bs[8][128];
  const int tid  = threadIdx.x;
  const int row0 = blockIdx.y * 128;
  const int col0 = blockIdx.x * 128;
  const int tx = tid & 15, ty = tid >> 4;
  const int lr = tid >> 1;
  const int lk = (tid & 1) * 4;

  float acc[8][8];
#pragma unroll
  for (int i = 0; i < 8; ++i)
#pragma unroll
    for (int j = 0; j < 8; ++j) acc[i][j] = 0.f;

  const float* Aptr = A + (size_t)(row0 + lr) * lda + lk;
  const int bcol = col0 + lr;
  const float* Bptr = (bcol < N) ? (B + (size_t)bcol * K + lk) : nullptr;

  float4 av = *(const float4*)(Aptr);
  float4 bv = Bptr ? *(const float4*)(Bptr) : make_float4(0.f, 0.f, 0.f, 0.f);

  for (int k0 = 0; k0 < K; k0 += 8) {
    As[lk + 0][lr] = av.x; As[lk + 1][lr] = av.y;
    As[lk + 2][lr] = av.z; As[lk + 3][lr] = av.w;
    Bs[lk + 0][lr] = bv.x; Bs[lk + 1][lr] = bv.y;
    Bs[lk + 2][lr] = bv.z; Bs[lk + 3][lr] = bv.w;
    if (k0 + 8 < K) {
      av = *(const float4*)(Aptr + k0 + 8);
      if (Bptr) bv = *(const float4*)(Bptr + k0 + 8);
    }
    __syncthreads();
#pragma unroll
    for (int k = 0; k < 8; ++k) {
      float a[8], b[8];
      *(float4*)&a[0] = *(const float4*)&As[k][ty * 4];
      *(float4*)&a[4] = *(const float4*)&As[k][64 + ty * 4];
      *(float4*)&b[0] = *(const float4*)&Bs[k][tx * 4];
      *(float4*)&b[4] = *(const float4*)&Bs[k][64 + tx * 4];
#pragma unroll
      for (int i = 0; i < 8; ++i)
#pragma unroll
        for (int j = 0; j < 8; ++j)
          acc[i][j] = fmaf(a[i], b[j], acc[i][j]);
    }
    __syncthreads();
  }

#pragma unroll
  for (int ih = 0; ih < 2; ++ih) {
#pragma unroll
    for (int i2 = 0; i2 < 4; ++i2) {
      int r = row0 + ih * 64 + ty * 4 + i2;
      if (r >= M) continue;
#pragma unroll
      for (int jh = 0; jh < 2; ++jh) {
        int c = col0 + jh * 64 + tx * 4;
        float vv[4];
#pragma unroll
        for (int j = 0; j < 4; ++j) {
          float v = acc[ih * 4 + i2][jh * 4 + j];
          if (ACT == 1) {
            v += bias[c + j];
            v = (v > 20.f) ? v : log1pf(expf(v));   // softplus
          }
          vv[j] = v;
        }
        if (c + 3 < N) {
          *(float4*)(C + (size_t)r * N + c) = make_float4(vv[0], vv[1], vv[2], vv[3]);
        } else {
          for (int j = 0; j < 4; ++j)
            if (c + j < N) C[(size_t)r * N + c + j] = vv[j];
        }
      }
    }
  }
}

// ---------------------------------------------------------------------------
// x_proj split-K, atomic-free: Pq[q][4096][96] = A[:, q-slice] @ W[:, q-slice]^T
// grid (MROWS/128, XKS); then xpj_reduce sums the XKS partials.
// ---------------------------------------------------------------------------
__global__ __launch_bounds__(256)
void xproj_splitk(const float* __restrict__ A, const float* __restrict__ W,
                  float* __restrict__ Pq) {
  __shared__ float As[8][128];
  __shared__ float Ws[8][96];
  const int tid  = threadIdx.x;
  const int row0 = blockIdx.x * 128;
  const int k0b  = blockIdx.y * (DINNER / XKS);
  const int tx = tid & 15, ty = tid >> 4;
  const int lr = tid >> 1, lk = (tid & 1) * 4;

  float acc[8][6];
#pragma unroll
  for (int i = 0; i < 8; ++i)
#pragma unroll
    for (int j = 0; j < 6; ++j) acc[i][j] = 0.f;

  const float* Ap = A + (size_t)(row0 + lr) * DINNER + lk;
  const float* Wp = (tid < 192) ? (W + (size_t)(tid >> 1) * DINNER + (tid & 1) * 4)
                                : nullptr;
  float4 av = *(const float4*)(Ap + k0b);
  float4 wv = Wp ? *(const float4*)(Wp + k0b) : make_float4(0.f, 0.f, 0.f, 0.f);

  for (int k0 = k0b; k0 < k0b + DINNER / XKS; k0 += 8) {
    As[lk + 0][lr] = av.x; As[lk + 1][lr] = av.y;
    As[lk + 2][lr] = av.z; As[lk + 3][lr] = av.w;
    if (Wp) {
      int j = tid >> 1, kk = (tid & 1) * 4;
      Ws[kk + 0][j] = wv.x; Ws[kk + 1][j] = wv.y;
      Ws[kk + 2][j] = wv.z; Ws[kk + 3][j] = wv.w;
    }
    if (k0 + 8 < k0b + DINNER / XKS) {
      av = *(const float4*)(Ap + k0 + 8);
      if (Wp) wv = *(const float4*)(Wp + k0 + 8);
    }
    __syncthreads();
#pragma unroll
    for (int kk = 0; kk < 8; ++kk) {
      float a[8], w[6];
      *(float4*)&a[0] = *(const float4*)&As[kk][ty * 8];
      *(float4*)&a[4] = *(const float4*)&As[kk][ty * 8 + 4];
#pragma unroll
      for (int j = 0; j < 6; ++j) w[j] = Ws[kk][tx * 6 + j];
#pragma unroll
      for (int i = 0; i < 8; ++i)
#pragma unroll
        for (int j = 0; j < 6; ++j)
          acc[i][j] = fmaf(a[i], w[j], acc[i][j]);
    }
    __syncthreads();
  }
  float* dst = Pq + (size_t)blockIdx.y * (MROWS * NPROJ);
#pragma unroll
  for (int i = 0; i < 8; ++i)
#pragma unroll
    for (int j = 0; j < 6; ++j)
      dst[(size_t)(row0 + ty * 8 + i) * NPROJ + tx * 6 + j] = acc[i][j];
}

__global__ __launch_bounds__(256)
void xpj_reduce(const float* __restrict__ Pq, float* __restrict__ xpb) {
  int idx = blockIdx.x * 256 + threadIdx.x;      // over MROWS*NPROJ = 393216
  float s = 0.f;
#pragma unroll
  for (int q = 0; q < XKS; ++q)
    s += Pq[(size_t)q * (MROWS * NPROJ) + idx];
  xpb[idx] = s;
}

// ---------------------------------------------------------------------------
// Causal depthwise conv (k=4) + bias + SiLU, float4-vectorized (4 channels).
// ---------------------------------------------------------------------------
__global__ __launch_bounds__(256)
void conv_silu_kernel(const float* __restrict__ xb, const float* __restrict__ cw,
                      const float* __restrict__ cb, float* __restrict__ xc) {
  int idx = (blockIdx.x * 256 + threadIdx.x) * 4;   // over MROWS*DINNER
  int d  = idx & (DINNER - 1);
  int ml = idx >> 11;
  int l  = ml & (LSEQ - 1);
  float4 W0 = *(const float4*)(cw + (d + 0) * 4);   // (w0,w1,w2,w3) ch d
  float4 W1 = *(const float4*)(cw + (d + 1) * 4);
  float4 W2 = *(const float4*)(cw + (d + 2) * 4);
  float4 W3 = *(const float4*)(cw + (d + 3) * 4);
  const float* base = xb + (size_t)ml * DINNER + d;
  float4 z4 = make_float4(0.f, 0.f, 0.f, 0.f);
  float4 r0  = *(const float4*)(base);
  float4 rm1 = (l >= 1) ? *(const float4*)(base - DINNER)     : z4;
  float4 rm2 = (l >= 2) ? *(const float4*)(base - 2 * DINNER) : z4;
  float4 rm3 = (l >= 3) ? *(const float4*)(base - 3 * DINNER) : z4;
  float4 bias = *(const float4*)(cb + d);
  float4 o;
  o.x = bias.x + r0.x * W0.w + rm1.x * W0.z + rm2.x * W0.y + rm3.x * W0.x;
  o.y = bias.y + r0.y * W1.w + rm1.y * W1.z + rm2.y * W1.y + rm3.y * W1.x;
  o.z = bias.z + r0.z * W2.w + rm1.z * W2.z + rm2.z * W2.y + rm3.z * W2.x;
  o.w = bias.w + r0.w * W3.w + rm1.w * W3.z + rm2.w * W3.y + rm3.w * W3.x;
  o.x = o.x / (1.f + expf(-o.x));
  o.y = o.y / (1.f + expf(-o.y));
  o.z = o.z / (1.f + expf(-o.z));
  o.w = o.w / (1.f + expf(-o.w));
  *(float4*)(xc + idx) = o;
}

// ---------------------------------------------------------------------------
// Chunked scan, h[16] in registers, one thread per (b, chunk, d).
// grid = 1024: bid -> b = bid>>9, c = (bid>>3)&63, dg = bid&7; d = dg*256+tid.
// dt input is POST-softplus. P/H layout: [b][c][d][16].
// ---------------------------------------------------------------------------
__global__ __launch_bounds__(256)
void scan_chunk_kernel(const float* __restrict__ dt, const float* __restrict__ xp,
                       const float* __restrict__ xc, const float* __restrict__ A_log,
                       float* __restrict__ P, float* __restrict__ H) {
  __shared__ float sbc[CLEN][32];
  const int tid = threadIdx.x;
  const int bid = blockIdx.x;
  const int b  = bid >> 9;
  const int c  = (bid >> 3) & 63;
  const int dg = bid & 7;
  const int d  = dg * 256 + tid;
  const int m0 = b * LSEQ + c * CLEN;
  {
    int r = tid >> 3, q = (tid & 7) * 4;
    *(float4*)&sbc[r][q] = *(const float4*)(xp + (size_t)(m0 + r) * NPROJ + DTRANK + q);
  }
  float a2[DSTATE], h[DSTATE];
#pragma unroll
  for (int n = 0; n < DSTATE; ++n) {
    a2[n] = -expf(A_log[d * DSTATE + n]) * 1.44269504f;
    h[n] = 0.f;
  }
  float dtsum = 0.f;
  __syncthreads();

  const float* dtp = dt + (size_t)m0 * DINNER + d;
  const float* xcp = xc + (size_t)m0 * DINNER + d;
  float ndt = dtp[0], nxc = xcp[0];
  for (int s = 0; s < CLEN; ++s) {
    float dtv = ndt, xv = nxc;
    int sp = (s + 1 < CLEN) ? s + 1 : s;
    ndt = dtp[(size_t)sp * DINNER];
    nxc = xcp[(size_t)sp * DINNER];
    dtsum += dtv;
    float dtx = dtv * xv;
    float Bv[16];
    *(float4*)&Bv[0]  = *(const float4*)&sbc[s][0];
    *(float4*)&Bv[4]  = *(const float4*)&sbc[s][4];
    *(float4*)&Bv[8]  = *(const float4*)&sbc[s][8];
    *(float4*)&Bv[12] = *(const float4*)&sbc[s][12];
#pragma unroll
    for (int n = 0; n < DSTATE; ++n) {
      float a = exp2f(dtv * a2[n]);
      h[n] = fmaf(a, h[n], dtx * Bv[n]);
    }
  }
  size_t o = ((size_t)(b * NCHUNK + c) * DINNER + d) * DSTATE;
  float4* Hp = (float4*)(H + o);
  Hp[0] = make_float4(h[0], h[1], h[2], h[3]);
  Hp[1] = make_float4(h[4], h[5], h[6], h[7]);
  Hp[2] = make_float4(h[8], h[9], h[10], h[11]);
  Hp[3] = make_float4(h[12], h[13], h[14], h[15]);
  float p[16];
#pragma unroll
  for (int n = 0; n < DSTATE; ++n) p[n] = exp2f(a2[n] * dtsum);
  float4* Pp = (float4*)(P + o);
  Pp[0] = make_float4(p[0], p[1], p[2], p[3]);
  Pp[1] = make_float4(p[4], p[5], p[6], p[7]);
  Pp[2] = make_float4(p[8], p[9], p[10], p[11]);
  Pp[3] = make_float4(p[12], p[13], p[14], p[15]);
}

// ---------------------------------------------------------------------------
// Stitch: serial over chunks per (b, d, n); overwrites H[c] with h_init.
// ---------------------------------------------------------------------------
__global__ __launch_bounds__(256)
void stitch_kernel(const float* __restrict__ P, float* __restrict__ H) {
  int idx = blockIdx.x * 256 + threadIdx.x;      // 65536 = BB * DINNER * 16
  int b = idx >> 15, e = idx & 32767;
  size_t base = (size_t)b * NCHUNK * 32768 + e;
  float h = 0.f;
  for (int c = 0; c < NCHUNK; ++c) {
    size_t o = base + (size_t)c * 32768;
    float p = P[o], q = H[o];
    H[o] = h;
    h = fmaf(p, h, q);
  }
}

// ---------------------------------------------------------------------------
// Output scan: recompute seeded with h_init, fused D-skip + silu(z) gate.
// dt and y alias (same buffer): each thread reads row s+1 before writing row s.
// ---------------------------------------------------------------------------
__global__ __launch_bounds__(256)
void scan_out_kernel(const float* dt, const float* __restrict__ xp,
                     const float* __restrict__ xc, const float* __restrict__ z,
                     const float* __restrict__ A_log, const float* __restrict__ Dp,
                     const float* __restrict__ Hinit, float* y) {
  __shared__ float sbc[CLEN][32];
  const int tid = threadIdx.x;
  const int bid = blockIdx.x;
  const int b  = bid >> 9;
  const int c  = (bid >> 3) & 63;
  const int dg = bid & 7;
  const int d  = dg * 256 + tid;
  const int m0 = b * LSEQ + c * CLEN;
  {
    int r = tid >> 3, q = (tid & 7) * 4;
    *(float4*)&sbc[r][q] = *(const float4*)(xp + (size_t)(m0 + r) * NPROJ + DTRANK + q);
  }
  float a2[DSTATE], h[DSTATE];
  size_t ho = ((size_t)(b * NCHUNK + c) * DINNER + d) * DSTATE;
  const float4* Hp = (const float4*)(Hinit + ho);
  float4 h0 = Hp[0], h1 = Hp[1], h2 = Hp[2], h3 = Hp[3];
  h[0]=h0.x; h[1]=h0.y; h[2]=h0.z; h[3]=h0.w;
  h[4]=h1.x; h[5]=h1.y; h[6]=h1.z; h[7]=h1.w;
  h[8]=h2.x; h[9]=h2.y; h[10]=h2.z; h[11]=h2.w;
  h[12]=h3.x; h[13]=h3.y; h[14]=h3.z; h[15]=h3.w;
#pragma unroll
  for (int n = 0; n < DSTATE; ++n)
    a2[n] = -expf(A_log[d * DSTATE + n]) * 1.44269504f;
  const float Dv = Dp[d];
  __syncthreads();

  const float* dtp = dt + (size_t)m0 * DINNER + d;
  const float* xcp = xc + (size_t)m0 * DINNER + d;
  const float* zp  = z  + (size_t)m0 * DINNER + d;
  float* yp = y + (size_t)m0 * DINNER + d;
  float ndt = dtp[0], nxc = xcp[0], nz = zp[0];
  for (int s = 0; s < CLEN; ++s) {
    float dtv = ndt, xv = nxc, zv = nz;
    int sp = (s + 1 < CLEN) ? s + 1 : s;
    ndt = dtp[(size_t)sp * DINNER];
    nxc = xcp[(size_t)sp * DINNER];
    nz  = zp[(size_t)sp * DINNER];
    float dtx = dtv * xv;
    float Bv[16], Cv[16];
    *(float4*)&Bv[0]  = *(const float4*)&sbc[s][0];
    *(float4*)&Bv[4]  = *(const float4*)&sbc[s][4];
    *(float4*)&Bv[8]  = *(const float4*)&sbc[s][8];
    *(float4*)&Bv[12] = *(const float4*)&sbc[s][12];
    *(float4*)&Cv[0]  = *(const float4*)&sbc[s][16];
    *(float4*)&Cv[4]  = *(const float4*)&sbc[s][20];
    *(float4*)&Cv[8]  = *(const float4*)&sbc[s][24];
    *(float4*)&Cv[12] = *(const float4*)&sbc[s][28];
    float yv = 0.f;
#pragma unroll
    for (int n = 0; n < DSTATE; ++n) {
      float a = exp2f(dtv * a2[n]);
      h[n] = fmaf(a, h[n], dtx * Bv[n]);
      yv = fmaf(h[n], Cv[n], yv);
    }
    yv = (yv + Dv * xv) * (zv / (1.f + expf(-zv)));
    yp[(size_t)s * DINNER] = yv;
  }
}

// ---------------------------------------------------------------------------
extern "C" void kernel_launch(void* const* d_in, const int* in_sizes, int n_in,
                              void* d_out, int out_size, void* d_ws, size_t ws_size,
                              hipStream_t stream) {
  const float* x          = (const float*)d_in[0];
  const float* in_proj_w  = (const float*)d_in[1];
  const float* conv_w     = (const float*)d_in[2];
  const float* conv_b     = (const float*)d_in[3];
  const float* x_proj_w   = (const float*)d_in[4];
  const float* dt_proj_w  = (const float*)d_in[5];
  const float* dt_proj_b  = (const float*)d_in[6];
  const float* A_log      = (const float*)d_in[7];
  const float* D_param    = (const float*)d_in[8];
  const float* out_proj_w = (const float*)d_in[9];
  float* out = (float*)d_out;
  float* ws  = (float*)d_ws;

  // workspace (floats); dtr and y alias xb; Pq (xproj partials) aliases P/H
  float* xb   = ws;                      // [4096,2048] x_branch -> dt -> y
  float* dtr  = xb;
  float* zb   = ws + 8388608;            // [4096,2048]
  float* xcb  = ws + 16777216;           // [4096,2048]
  float* xpb  = ws + 25165824;           // [4096,96]
  float* Pbuf = ws + 25559040;           // [2,64,2048,16]
  float* Hbuf = ws + 29753344;           // [2,64,2048,16]
  float* Pq   = Pbuf;                    // [16,4096,96] = 6.3M floats < P+H

  dim3 blk(256);
  // 1. in_proj (fused x_branch + z): one N=4096 MFMA GEMM, dual output
  gemm_mfma<<<dim3((MROWS / 128) * (2 * DINNER / 128)), blk, 0, stream>>>(
      x, in_proj_w, xb, zb, MROWS, 2 * DINNER, DMODEL, DINNER);
  // 2. causal depthwise conv + SiLU (vectorized)
  conv_silu_kernel<<<(MROWS * DINNER) / 1024, blk, 0, stream>>>(xb, conv_w, conv_b, xcb);
  // 3. x_proj split-K (atomic-free partials + reduce)
  xproj_splitk<<<dim3(MROWS / 128, XKS), blk, 0, stream>>>(xcb, x_proj_w, Pq);
  xpj_reduce<<<(MROWS * NPROJ) / 256, blk, 0, stream>>>(Pq, xpb);
  // 4. dt_proj with fused bias+softplus; overwrites x_branch
  gemm_tn<1><<<dim3(DINNER / 128, MROWS / 128), blk, 0, stream>>>(
      xpb, dt_proj_w, dtr, dt_proj_b, MROWS, DINNER, DTRANK, NPROJ);
  // 5. chunked scan: A (chunk transitions), B (stitch), C (output + gate)
  scan_chunk_kernel<<<dim3(BB * NCHUNK * 8), blk, 0, stream>>>(
      dtr, xpb, xcb, A_log, Pbuf, Hbuf);
  stitch_kernel<<<dim3(BB * DINNER * DSTATE / 256), blk, 0, stream>>>(Pbuf, Hbuf);
  scan_out_kernel<<<dim3(BB * NCHUNK * 8), blk, 0, stream>>>(
      dtr, xpb, xcb, zb, A_log, D_param, Hbuf, xb);
  // 6. out_proj (MFMA)
  gemm_mfma<<<dim3((MROWS / 128) * (DMODEL / 128)), blk, 0, stream>>>(
      xb, out_proj_w, out, out, MROWS, DMODEL, DINNER, DMODEL);
}